// Round 1
// 287.986 us; speedup vs baseline: 1.0462x; 1.0462x over previous
//
#include <hip/hip_runtime.h>
#include <hip/hip_bf16.h>
#include <stdint.h>

// Workspace layout (bytes):
//  outbf  [0,        33554432)   out cast to bf16        (B*T*D)
//  vbf    [33554432, 67108864)   V = out @ W_write^T, bf16
//  wwbf   [67108864, 69206016)   W_write bf16
//  wrbf   [69206016, 71303168)   W_read  bf16
//  intra  [71303168, 104857600)  intra reads bf16 (flat B,T,D layout)
//  U      [104857600,138412032)  per-chunk outer products bf16 [BH][64][64*64]
//  Wst    [138412032,171966464)  pre-chunk W states bf16 [BH][64][64*64]
//  reads  [171966464,205520896)  alpha*(inter+intra) bf16 (flat B,T,D)

typedef __bf16 bf16x8 __attribute__((ext_vector_type(8)));
typedef float f32x4 __attribute__((ext_vector_type(4)));

#define GAS __attribute__((address_space(1)))
#define LAS __attribute__((address_space(3)))

__device__ __forceinline__ unsigned short f2bf(float f) {
  unsigned u = __float_as_uint(f);
  u = (u + 0x7fffu + ((u >> 16) & 1u)) >> 16;   // RNE
  return (unsigned short)u;
}
__device__ __forceinline__ float bf2f(unsigned short h) {
  return __uint_as_float(((unsigned)h) << 16);
}

// ---------------------------------------------------------------- cast f32->bf16
__global__ __launch_bounds__(256) void cast_f32_to_bf16(
    const float* __restrict__ src, unsigned short* __restrict__ dst, int n8) {
  int i = blockIdx.x * 256 + threadIdx.x;  // handles 8 elements
  if (i >= n8) return;
  const float4* s = (const float4*)src + (size_t)i * 2;
  float4 f0 = s[0], f1 = s[1];
  union { uint4 u4; unsigned short us[8]; } o;
  o.us[0] = f2bf(f0.x); o.us[1] = f2bf(f0.y); o.us[2] = f2bf(f0.z); o.us[3] = f2bf(f0.w);
  o.us[4] = f2bf(f1.x); o.us[5] = f2bf(f1.y); o.us[6] = f2bf(f1.z); o.us[7] = f2bf(f1.w);
  ((uint4*)dst)[i] = o.u4;
}

// both 1024x1024 weights in one launch: i8 < 131072 -> W_write, else W_read
__global__ __launch_bounds__(256) void cast_weights(
    const float* __restrict__ w1, const float* __restrict__ w2,
    unsigned short* __restrict__ dst) {
  int i = blockIdx.x * 256 + threadIdx.x;  // 262144 total (2*1048576/8)
  const float* src = (i < 131072) ? w1 : w2;
  int j = (i < 131072) ? i : i - 131072;
  const float4* s = (const float4*)src + (size_t)j * 2;
  float4 f0 = s[0], f1 = s[1];
  union { uint4 u4; unsigned short us[8]; } o;
  o.us[0] = f2bf(f0.x); o.us[1] = f2bf(f0.y); o.us[2] = f2bf(f0.z); o.us[3] = f2bf(f0.w);
  o.us[4] = f2bf(f1.x); o.us[5] = f2bf(f1.y); o.us[6] = f2bf(f1.z); o.us[7] = f2bf(f1.w);
  ((uint4*)dst)[i] = o.u4;
}

// XCD-aware block swizzle for the 1024-block GEMMs (M/128=128 x N/128=8).
__device__ __forceinline__ void swizzle_bm_bn(int id, int& bm, int& bn) {
  int x = id & 7;
  int s = id >> 3;
  bn = s & 7;
  bm = ((s >> 3) << 3) | x;
}

// ---------------------------------------------------------------- GEMM C = A * B^T (bf16 out)
__global__ __launch_bounds__(256, 4) void gemm_bt_bf16out(
    const unsigned short* __restrict__ A, const unsigned short* __restrict__ B,
    unsigned short* __restrict__ C, int M, int N, int K) {
  __shared__ unsigned short As[2][128 * 32];
  __shared__ unsigned short Bs[2][128 * 32];
  int tid = threadIdx.x;
  int l = tid & 63, w = tid >> 6;
  int bm, bn;
  swizzle_bm_bn(blockIdx.x, bm, bn);
  int wm = (w >> 1) * 64, wn = (w & 1) * 64;
  f32x4 acc[4][4];
#pragma unroll
  for (int mi = 0; mi < 4; mi++)
#pragma unroll
    for (int ni = 0; ni < 4; ni++) acc[mi][ni] = (f32x4){0.f, 0.f, 0.f, 0.f};
  const unsigned short* Ab = A + (size_t)bm * 128 * K;
  const unsigned short* Bb = B + (size_t)bn * 128 * K;
  int lr = l >> 2, lc = (l & 3) * 8;
  int lm = l & 15, q4 = l >> 4;
  const int nit = K >> 5;
#pragma unroll
  for (int q = 0; q < 2; q++) {
    int g = (w * 2 + q) * 16 + lr;
    __builtin_amdgcn_global_load_lds((GAS void*)(void*)(Ab + (size_t)g * K + lc),
                                     (LAS void*)(&As[0][(w * 2 + q) * 512]), 16, 0, 0);
    __builtin_amdgcn_global_load_lds((GAS void*)(void*)(Bb + (size_t)g * K + lc),
                                     (LAS void*)(&Bs[0][(w * 2 + q) * 512]), 16, 0, 0);
  }
  for (int it = 0; it < nit; it++) {
    __syncthreads();
    int buf = it & 1;
    if (it + 1 < nit) {
      int k0 = (it + 1) << 5;
#pragma unroll
      for (int q = 0; q < 2; q++) {
        int g = (w * 2 + q) * 16 + lr;
        __builtin_amdgcn_global_load_lds((GAS void*)(void*)(Ab + (size_t)g * K + k0 + lc),
                                         (LAS void*)(&As[buf ^ 1][(w * 2 + q) * 512]), 16, 0, 0);
        __builtin_amdgcn_global_load_lds((GAS void*)(void*)(Bb + (size_t)g * K + k0 + lc),
                                         (LAS void*)(&Bs[buf ^ 1][(w * 2 + q) * 512]), 16, 0, 0);
      }
    }
    bf16x8 a[4], b[4];
#pragma unroll
    for (int mi = 0; mi < 4; mi++) a[mi] = *(const bf16x8*)&As[buf][(wm + mi * 16 + lm) * 32 + q4 * 8];
#pragma unroll
    for (int ni = 0; ni < 4; ni++) b[ni] = *(const bf16x8*)&Bs[buf][(wn + ni * 16 + lm) * 32 + q4 * 8];
#pragma unroll
    for (int mi = 0; mi < 4; mi++)
#pragma unroll
      for (int ni = 0; ni < 4; ni++)
        acc[mi][ni] = __builtin_amdgcn_mfma_f32_16x16x32_bf16(a[mi], b[ni], acc[mi][ni], 0, 0, 0);
  }
#pragma unroll
  for (int mi = 0; mi < 4; mi++)
#pragma unroll
    for (int ni = 0; ni < 4; ni++) {
      int r0 = bm * 128 + wm + mi * 16 + q4 * 4;
      int col = bn * 128 + wn + ni * 16 + lm;
#pragma unroll
      for (int j = 0; j < 4; j++)
        C[(size_t)(r0 + j) * N + col] = f2bf(acc[mi][ni][j]);
    }
}

// Same structure; C = base(bf16) + A*B^T (fp32 out).
__global__ __launch_bounds__(256, 4) void gemm_bt_addout(
    const unsigned short* __restrict__ A, const unsigned short* __restrict__ B,
    const unsigned short* __restrict__ base_bf, float* __restrict__ C, int M, int N, int K) {
  __shared__ unsigned short As[2][128 * 32];
  __shared__ unsigned short Bs[2][128 * 32];
  int tid = threadIdx.x;
  int l = tid & 63, w = tid >> 6;
  int bm, bn;
  swizzle_bm_bn(blockIdx.x, bm, bn);
  int wm = (w >> 1) * 64, wn = (w & 1) * 64;
  int lr = l >> 2, lc = (l & 3) * 8;
  int lm = l & 15, q4 = l >> 4;
  f32x4 acc[4][4];
#pragma unroll
  for (int mi = 0; mi < 4; mi++)
#pragma unroll
    for (int ni = 0; ni < 4; ni++) {
      int r0 = bm * 128 + wm + mi * 16 + q4 * 4;
      int col = bn * 128 + wn + ni * 16 + lm;
#pragma unroll
      for (int j = 0; j < 4; j++)
        acc[mi][ni][j] = bf2f(base_bf[(size_t)(r0 + j) * N + col]);
    }
  const unsigned short* Ab = A + (size_t)bm * 128 * K;
  const unsigned short* Bb = B + (size_t)bn * 128 * K;
  const int nit = K >> 5;
#pragma unroll
  for (int q = 0; q < 2; q++) {
    int g = (w * 2 + q) * 16 + lr;
    __builtin_amdgcn_global_load_lds((GAS void*)(void*)(Ab + (size_t)g * K + lc),
                                     (LAS void*)(&As[0][(w * 2 + q) * 512]), 16, 0, 0);
    __builtin_amdgcn_global_load_lds((GAS void*)(void*)(Bb + (size_t)g * K + lc),
                                     (LAS void*)(&Bs[0][(w * 2 + q) * 512]), 16, 0, 0);
  }
  for (int it = 0; it < nit; it++) {
    __syncthreads();
    int buf = it & 1;
    if (it + 1 < nit) {
      int k0 = (it + 1) << 5;
#pragma unroll
      for (int q = 0; q < 2; q++) {
        int g = (w * 2 + q) * 16 + lr;
        __builtin_amdgcn_global_load_lds((GAS void*)(void*)(Ab + (size_t)g * K + k0 + lc),
                                         (LAS void*)(&As[buf ^ 1][(w * 2 + q) * 512]), 16, 0, 0);
        __builtin_amdgcn_global_load_lds((GAS void*)(void*)(Bb + (size_t)g * K + k0 + lc),
                                         (LAS void*)(&Bs[buf ^ 1][(w * 2 + q) * 512]), 16, 0, 0);
      }
    }
    bf16x8 a[4], b[4];
#pragma unroll
    for (int mi = 0; mi < 4; mi++) a[mi] = *(const bf16x8*)&As[buf][(wm + mi * 16 + lm) * 32 + q4 * 8];
#pragma unroll
    for (int ni = 0; ni < 4; ni++) b[ni] = *(const bf16x8*)&Bs[buf][(wn + ni * 16 + lm) * 32 + q4 * 8];
#pragma unroll
    for (int mi = 0; mi < 4; mi++)
#pragma unroll
      for (int ni = 0; ni < 4; ni++)
        acc[mi][ni] = __builtin_amdgcn_mfma_f32_16x16x32_bf16(a[mi], b[ni], acc[mi][ni], 0, 0, 0);
  }
#pragma unroll
  for (int mi = 0; mi < 4; mi++)
#pragma unroll
    for (int ni = 0; ni < 4; ni++) {
      int r0 = bm * 128 + wm + mi * 16 + q4 * 4;
      int col = bn * 128 + wn + ni * 16 + lm;
#pragma unroll
      for (int j = 0; j < 4; j++)
        C[(size_t)(r0 + j) * N + col] = acc[mi][ni][j];
    }
}

// ---------------------------------------------------------------- per-chunk local work
// grid (c=64, bh=64), 256 thr. Computes S=rk wk^T masked, intra=(S.M) v, U=(v*g_w)^T wk.
__global__ __launch_bounds__(256) void chunk_local(
    const unsigned short* __restrict__ rkg,   // outbf flat [B*T*D]
    const unsigned short* __restrict__ vg,    // vbf flat
    const float* __restrict__ decay,
    unsigned short* __restrict__ intra_bf,    // flat [B*T*D]
    unsigned short* __restrict__ U_bf) {      // [BH][64][64*64]
  int c = blockIdx.x, bh = blockIdx.y;
  int b = bh >> 4, h = bh & 15;
  int tid = threadIdx.x, l = tid & 63, w = tid >> 6;
  float gamma = 1.0f / (1.0f + __expf(-decay[h]));
  float lg = __logf(gamma);

  __shared__ unsigned short rk_s[64 * 72];
  __shared__ unsigned short wk_s[64 * 72];
  __shared__ unsigned short wkT_s[64 * 72];
  __shared__ unsigned short vT_s[64 * 72];
  __shared__ unsigned short S_s[64 * 72];

  const size_t rowbase = (((size_t)b * 4096 + (size_t)c * 64) * 1024) + h * 64;

#pragma unroll
  for (int r = 0; r < 2; r++) {
    int e = r * 256 + tid;
    int p = e >> 3, seg = e & 7;
    uint4 dr = *(const uint4*)(rkg + rowbase + (size_t)p * 1024 + seg * 8);
    *(uint4*)&rk_s[p * 72 + seg * 8] = dr;
    uint4 dv = *(const uint4*)(vg + rowbase + (size_t)p * 1024 + seg * 8);
    {
      unsigned uu[4] = {dv.x, dv.y, dv.z, dv.w};
#pragma unroll
      for (int qq = 0; qq < 4; qq++) {
        vT_s[(seg * 8 + qq * 2) * 72 + p] = (unsigned short)(uu[qq] & 0xffffu);
        vT_s[(seg * 8 + qq * 2 + 1) * 72 + p] = (unsigned short)(uu[qq] >> 16);
      }
    }
    int tg = c * 64 + p - 1;  // wk = rk shifted right by one token (zero at t=0)
    uint4 dw = make_uint4(0u, 0u, 0u, 0u);
    if (tg >= 0) dw = *(const uint4*)(rkg + ((size_t)b * 4096 + tg) * 1024 + h * 64 + seg * 8);
    *(uint4*)&wk_s[p * 72 + seg * 8] = dw;
    {
      unsigned uu[4] = {dw.x, dw.y, dw.z, dw.w};
#pragma unroll
      for (int qq = 0; qq < 4; qq++) {
        wkT_s[(seg * 8 + qq * 2) * 72 + p] = (unsigned short)(uu[qq] & 0xffffu);
        wkT_s[(seg * 8 + qq * 2 + 1) * 72 + p] = (unsigned short)(uu[qq] >> 16);
      }
    }
  }
  __syncthreads();

  int lm = l & 15, q4 = l >> 4;

  // Phase 1: S = rk @ wk^T, apply mask M, store bf16
  {
    bf16x8 a0 = *(const bf16x8*)&rk_s[(w * 16 + lm) * 72 + q4 * 8];
    bf16x8 a1 = *(const bf16x8*)&rk_s[(w * 16 + lm) * 72 + 32 + q4 * 8];
#pragma unroll
    for (int ni = 0; ni < 4; ni++) {
      bf16x8 b0 = *(const bf16x8*)&wk_s[(ni * 16 + lm) * 72 + q4 * 8];
      bf16x8 b1 = *(const bf16x8*)&wk_s[(ni * 16 + lm) * 72 + 32 + q4 * 8];
      f32x4 acc = {0.f, 0.f, 0.f, 0.f};
      acc = __builtin_amdgcn_mfma_f32_16x16x32_bf16(a0, b0, acc, 0, 0, 0);
      acc = __builtin_amdgcn_mfma_f32_16x16x32_bf16(a1, b1, acc, 0, 0, 0);
#pragma unroll
      for (int j = 0; j < 4; j++) {
        int p = w * 16 + q4 * 4 + j;
        int q = ni * 16 + lm;
        float m = (p > q) ? __expf(lg * (float)(p - 1 - q)) : 0.0f;
        S_s[p * 72 + q] = f2bf(acc[j] * m);
      }
    }
  }
  __syncthreads();

  // Phase 2: intra = (S.M) @ v
  {
    bf16x8 a0 = *(const bf16x8*)&S_s[(w * 16 + lm) * 72 + q4 * 8];
    bf16x8 a1 = *(const bf16x8*)&S_s[(w * 16 + lm) * 72 + 32 + q4 * 8];
#pragma unroll
    for (int ni = 0; ni < 4; ni++) {
      bf16x8 b0 = *(const bf16x8*)&vT_s[(ni * 16 + lm) * 72 + q4 * 8];
      bf16x8 b1 = *(const bf16x8*)&vT_s[(ni * 16 + lm) * 72 + 32 + q4 * 8];
      f32x4 acc = {0.f, 0.f, 0.f, 0.f};
      acc = __builtin_amdgcn_mfma_f32_16x16x32_bf16(a0, b0, acc, 0, 0, 0);
      acc = __builtin_amdgcn_mfma_f32_16x16x32_bf16(a1, b1, acc, 0, 0, 0);
#pragma unroll
      for (int j = 0; j < 4; j++) {
        int p = w * 16 + q4 * 4 + j;
        int i = ni * 16 + lm;
        intra_bf[rowbase + (size_t)p * 1024 + i] = f2bf(acc[j]);
      }
    }
  }

  // Phase 3: U = (v * g_w)^T @ wk
  {
    bf16x8 a0 = *(const bf16x8*)&vT_s[(w * 16 + lm) * 72 + q4 * 8];
    bf16x8 a1 = *(const bf16x8*)&vT_s[(w * 16 + lm) * 72 + 32 + q4 * 8];
#pragma unroll
    for (int jj = 0; jj < 8; jj++) {
      int p0 = q4 * 8 + jj;
      a0[jj] = (__bf16)((float)a0[jj] * __expf(lg * (float)(63 - p0)));
      a1[jj] = (__bf16)((float)a1[jj] * __expf(lg * (float)(63 - (p0 + 32))));
    }
    size_t ub = ((size_t)bh * 64 + c) * 4096;
#pragma unroll
    for (int nj = 0; nj < 4; nj++) {
      bf16x8 b0 = *(const bf16x8*)&wkT_s[(nj * 16 + lm) * 72 + q4 * 8];
      bf16x8 b1 = *(const bf16x8*)&wkT_s[(nj * 16 + lm) * 72 + 32 + q4 * 8];
      f32x4 acc = {0.f, 0.f, 0.f, 0.f};
      acc = __builtin_amdgcn_mfma_f32_16x16x32_bf16(a0, b0, acc, 0, 0, 0);
      acc = __builtin_amdgcn_mfma_f32_16x16x32_bf16(a1, b1, acc, 0, 0, 0);
#pragma unroll
      for (int j = 0; j < 4; j++) {
        int i = w * 16 + q4 * 4 + j;
        int col = nj * 16 + lm;
        U_bf[ub + i * 64 + col] = f2bf(acc[j]);
      }
    }
  }
}

// ---------------------------------------------------------------- parallel weighted prefix scan
// Wst[bh][c] = sum_{c'<c} gC^(c-1-c') U[bh][c']  (pre-chunk state, bf16 out, fp32 chain).
// gC is a per-head SCALAR -> the recurrence is elementwise; no need to serialize the matmul.
// grid (8 n-slices, 64 bh), 256 thr; thread owns 2 elements, full-unrolled c-loop:
// all 64 loads independent -> deep pipelining; numerics identical to the old serial kernel.
__global__ __launch_bounds__(256) void scan_w(
    const unsigned short* __restrict__ U_bf, const float* __restrict__ decay,
    unsigned short* __restrict__ Wst) {
  int nsl = blockIdx.x, bh = blockIdx.y;
  int h = bh & 15;
  float gamma = 1.0f / (1.0f + __expf(-decay[h]));
  float gC = __expf(64.0f * __logf(gamma));
  int n0 = nsl * 512 + threadIdx.x * 2;
  const unsigned short* Ub = U_bf + (size_t)bh * 64 * 4096 + n0;
  unsigned short* Wb = Wst + (size_t)bh * 64 * 4096 + n0;
  float w0 = 0.f, w1 = 0.f;
#pragma unroll
  for (int c = 0; c < 64; c++) {
    unsigned u = *(const unsigned*)(Ub + (size_t)c * 4096);
    ushort2 sv;
    sv.x = f2bf(w0);
    sv.y = f2bf(w1);
    *(ushort2*)(Wb + (size_t)c * 4096) = sv;
    w0 = gC * w0 + bf2f((unsigned short)(u & 0xffffu));
    w1 = gC * w1 + bf2f((unsigned short)(u >> 16));
  }
}

// ---------------------------------------------------------------- inter + combine (parallel)
// grid (c=64, bh=64), 256 thr. inter = g_p (.) (rk_c @ W_c^T); reads = alpha*(inter+intra).
// Fully parallel (no serial chain), LDS-staged intra kills the old dependent epilogue load.
__global__ __launch_bounds__(256) void inter_combine(
    const unsigned short* __restrict__ rkg, const unsigned short* __restrict__ Wst,
    const unsigned short* __restrict__ intra_bf,
    const float* __restrict__ decay, const float* __restrict__ log_alpha,
    unsigned short* __restrict__ reads_bf) {
  int c = blockIdx.x, bh = blockIdx.y;
  int b = bh >> 4, h = bh & 15;
  int tid = threadIdx.x, l = tid & 63, w = tid >> 6;
  int lm = l & 15, q4 = l >> 4;
  float gamma = 1.0f / (1.0f + __expf(-decay[h]));
  float lg = __logf(gamma);
  float alpha = __expf(log_alpha[h]);

  __shared__ unsigned short rk_s[64 * 72];
  __shared__ unsigned short W_s[64 * 72];
  __shared__ unsigned short in_s[64 * 72];

  const size_t rowbase = (((size_t)b * 4096 + (size_t)c * 64) * 1024) + h * 64;
  const size_t wbase = ((size_t)bh * 64 + c) * 4096;

#pragma unroll
  for (int r = 0; r < 2; r++) {
    int e = r * 256 + tid;
    int p = e >> 3, seg = (e & 7) * 8;
    *(uint4*)&rk_s[p * 72 + seg] = *(const uint4*)(rkg + rowbase + (size_t)p * 1024 + seg);
    *(uint4*)&in_s[p * 72 + seg] = *(const uint4*)(intra_bf + rowbase + (size_t)p * 1024 + seg);
    *(uint4*)&W_s[p * 72 + seg] = *(const uint4*)(Wst + wbase + (size_t)p * 64 + seg);
  }
  __syncthreads();

  // MFMA: wave w covers tokens w*16..w*16+15 (M=16), N=64 in 4 tiles, K=64 in 2 steps
  bf16x8 a0 = *(const bf16x8*)&rk_s[(w * 16 + lm) * 72 + q4 * 8];
  bf16x8 a1 = *(const bf16x8*)&rk_s[(w * 16 + lm) * 72 + 32 + q4 * 8];
#pragma unroll
  for (int ni = 0; ni < 4; ni++) {
    bf16x8 b0 = *(const bf16x8*)&W_s[(ni * 16 + lm) * 72 + q4 * 8];
    bf16x8 b1 = *(const bf16x8*)&W_s[(ni * 16 + lm) * 72 + 32 + q4 * 8];
    f32x4 acc = {0.f, 0.f, 0.f, 0.f};
    acc = __builtin_amdgcn_mfma_f32_16x16x32_bf16(a0, b0, acc, 0, 0, 0);
    acc = __builtin_amdgcn_mfma_f32_16x16x32_bf16(a1, b1, acc, 0, 0, 0);
#pragma unroll
    for (int j = 0; j < 4; j++) {
      int p = w * 16 + q4 * 4 + j;   // token within chunk
      int i = ni * 16 + lm;          // state row (output col)
      float gp = __expf(lg * (float)p);
      reads_bf[rowbase + (size_t)p * 1024 + i] =
          f2bf(alpha * (acc[j] * gp + bf2f(in_s[p * 72 + i])));
    }
  }
}

// ----------------------------------------------------------------
extern "C" void kernel_launch(void* const* d_in, const int* in_sizes, int n_in,
                              void* d_out, int out_size, void* d_ws, size_t ws_size,
                              hipStream_t stream) {
  const float* out_f = (const float*)d_in[0];
  const float* Ww = (const float*)d_in[1];
  const float* Wr = (const float*)d_in[2];
  const float* decay = (const float*)d_in[3];
  const float* lalpha = (const float*)d_in[4];

  char* ws = (char*)d_ws;
  unsigned short* outbf = (unsigned short*)(ws + 0);
  unsigned short* vbf   = (unsigned short*)(ws + 33554432);
  unsigned short* wwbf  = (unsigned short*)(ws + 67108864);  // wrbf adjacent at +2MB
  unsigned short* wrbf  = (unsigned short*)(ws + 69206016);
  unsigned short* intra = (unsigned short*)(ws + 71303168);
  unsigned short* U     = (unsigned short*)(ws + 104857600);
  unsigned short* Wst   = (unsigned short*)(ws + 138412032);
  unsigned short* reads = (unsigned short*)(ws + 171966464);

  cast_f32_to_bf16<<<dim3(8192), 256, 0, stream>>>(out_f, outbf, 16777216 / 8);
  cast_weights<<<dim3(1024), 256, 0, stream>>>(Ww, Wr, wwbf);

  // V = out @ W_write^T   (M=B*T=16384, N=D=1024, K=D=1024)
  gemm_bt_bf16out<<<dim3(1024), 256, 0, stream>>>(outbf, wwbf, vbf, 16384, 1024, 1024);

  chunk_local<<<dim3(64, 64), 256, 0, stream>>>(outbf, vbf, decay, intra, U);

  // parallel scan of W states (replaces the serial scan_inter)
  scan_w<<<dim3(8, 64), 256, 0, stream>>>(U, decay, Wst);
  inter_combine<<<dim3(64, 64), 256, 0, stream>>>(outbf, Wst, intra, decay, lalpha, reads);

  // final = out + reads @ W_read^T (base added from bf16 copy)
  gemm_bt_addout<<<dim3(1024), 256, 0, stream>>>(reads, wrbf, outbf, (float*)d_out,
                                                 16384, 1024, 1024);
}